// Round 12
// baseline (1646.299 us; speedup 1.0000x reference)
//
#include <hip/hip_runtime.h>

#define K_DIM 256
__device__ __forceinline__ float lrelu_f(float x) { return x >= 0.f ? x : 0.2f * x; }

// ---------------- graph prep kernels ----------------

__global__ __launch_bounds__(256) void hist_kernel(const int* __restrict__ dst,
                                                   int* __restrict__ cnt, int E) {
  int e = blockIdx.x * 256 + threadIdx.x;
  if (e < E) atomicAdd(&cnt[dst[e]], 1);
}

__global__ __launch_bounds__(256) void dinv_kernel(const int* __restrict__ cnt,
                                                   float* __restrict__ dinv, int n) {
  int i = blockIdx.x * 256 + threadIdx.x;
  if (i < n) dinv[i] = rsqrtf((float)cnt[i] + 1.0f);
}

__global__ __launch_bounds__(256) void scan1_kernel(const int* __restrict__ cnt,
                                                    int* __restrict__ incl,
                                                    int* __restrict__ bsum, int n) {
  __shared__ int sm[256];
  int t = threadIdx.x;
  int i = blockIdx.x * 256 + t;
  int v = (i < n) ? cnt[i] : 0;
  sm[t] = v;
  __syncthreads();
  for (int off = 1; off < 256; off <<= 1) {
    int u = (t >= off) ? sm[t - off] : 0;
    __syncthreads();
    sm[t] += u;
    __syncthreads();
  }
  if (i < n) incl[i] = sm[t];
  if (t == 255) bsum[blockIdx.x] = sm[255];
}

__global__ __launch_bounds__(256) void scan2_kernel(const int* __restrict__ bsum,
                                                    int* __restrict__ boff, int nb) {
  __shared__ int sm[256];
  int t = threadIdx.x;
  int v = (t < nb) ? bsum[t] : 0;
  sm[t] = v;
  __syncthreads();
  for (int off = 1; off < 256; off <<= 1) {
    int u = (t >= off) ? sm[t - off] : 0;
    __syncthreads();
    sm[t] += u;
    __syncthreads();
  }
  boff[t] = sm[t] - v;  // exclusive
}

__global__ __launch_bounds__(256) void scan3_kernel(const int* __restrict__ incl,
                                                    const int* __restrict__ boff,
                                                    int* __restrict__ rowptr, int n) {
  int i = blockIdx.x * 256 + threadIdx.x;
  if (i < n) rowptr[i + 1] = incl[i] + boff[blockIdx.x];
  if (i == 0) rowptr[0] = 0;
}

__global__ __launch_bounds__(256) void scatter_kernel(const int* __restrict__ src,
                                                      const int* __restrict__ dst,
                                                      const int* __restrict__ rowptr,
                                                      int* __restrict__ cursor,
                                                      const float* __restrict__ dinv,
                                                      int* __restrict__ esrc,
                                                      float* __restrict__ ew, int E) {
  int e = blockIdx.x * 256 + threadIdx.x;
  if (e < E) {
    int d = dst[e];
    int p = rowptr[d] + atomicAdd(&cursor[d], 1);
    int s = src[e];
    esrc[p] = s;
    ew[p] = dinv[s];
  }
}

// ---- degree-bucket sort (R10): nodes processed in degree order so each wave's
// 8 lane-groups have equal edge-loop trip counts (kills gather divergence).
// Per-node edge order unchanged -> bit-identical results.

__global__ __launch_bounds__(256) void bucket_hist_kernel(const int* __restrict__ cnt,
                                                          int* __restrict__ bhist, int n) {
  int i = blockIdx.x * 256 + threadIdx.x;
  if (i < n) atomicAdd(&bhist[min(cnt[i], 63)], 1);
}

__global__ __launch_bounds__(64) void bucket_scan_kernel(const int* __restrict__ bhist,
                                                         int* __restrict__ boffs) {
  __shared__ int sm[64];
  int t = threadIdx.x;
  int v = bhist[t];
  sm[t] = v;
  __syncthreads();
  for (int off = 1; off < 64; off <<= 1) {
    int u = (t >= off) ? sm[t - off] : 0;
    __syncthreads();
    sm[t] += u;
    __syncthreads();
  }
  boffs[t] = sm[t] - v;  // exclusive
}

__global__ __launch_bounds__(256) void bucket_scatter_kernel(const int* __restrict__ cnt,
                                                             const int* __restrict__ boffs,
                                                             int* __restrict__ bcur,
                                                             int* __restrict__ order, int n) {
  int i = blockIdx.x * 256 + threadIdx.x;
  if (i < n) {
    int b = min(cnt[i], 63);
    int p = boffs[b] + atomicAdd(&bcur[b], 1);
    order[p] = i;
  }
}

// ---------------- GEMM (R8: best known, ~100us/dispatch, 52% of fp32 peak) ----------------
// 128x128 tile, 256 threads, 8x8 microtile, BK=32, PAD=132 (2-way staging conflict).
// R9 LESSON: bigger microtile (16x8, 128thr) -> 6 waves/CU -> latency-bound, SLOWER.
// outputs/thread x threads = const: 8x8 @ 12 waves/CU is this family's optimum.
// R6 LESSON: dbuf+prefetch -> VGPR 184 -> 9% occ -> 2x slower. Keep single-buffer.

template <bool LRELU, int NCOLS>
__global__ __launch_bounds__(256) void gemm_kernel(const float* __restrict__ A,
                                                   const float* __restrict__ W,
                                                   float* __restrict__ H, int M) {
  constexpr int BK = 32;
  constexpr int PAD = 132;
  __shared__ float As[BK][PAD];
  __shared__ float Ws[BK][PAD];
  const int bm = blockIdx.x * 128;
  const int bn = blockIdx.y * 128;
  const int tid = threadIdx.x;
  const int tx = tid & 15;
  const int ty = tid >> 4;
  const int lr = tid >> 2;
  const int lk = (tid & 3) << 2;

  float acc[2][2][4][4];
#pragma unroll
  for (int a = 0; a < 2; a++)
#pragma unroll
    for (int b = 0; b < 2; b++)
#pragma unroll
      for (int i = 0; i < 4; i++)
#pragma unroll
        for (int j = 0; j < 4; j++) acc[a][b][i][j] = 0.f;

  for (int k0 = 0; k0 < K_DIM; k0 += BK) {
#pragma unroll
    for (int kh = 0; kh < 2; ++kh) {
      const int ks = kh * 16 + lk;
#pragma unroll
      for (int h = 0; h < 2; ++h) {
        int row = bm + h * 64 + lr;
        int rc = row < M ? row : M - 1;
        float4 v = *(const float4*)(A + (size_t)rc * K_DIM + k0 + ks);
        if (LRELU) {
          v.x = lrelu_f(v.x); v.y = lrelu_f(v.y); v.z = lrelu_f(v.z); v.w = lrelu_f(v.w);
        }
        As[ks + 0][h * 64 + lr] = v.x;
        As[ks + 1][h * 64 + lr] = v.y;
        As[ks + 2][h * 64 + lr] = v.z;
        As[ks + 3][h * 64 + lr] = v.w;
      }
#pragma unroll
      for (int h = 0; h < 2; ++h) {
        int row = bn + h * 64 + lr;
        float4 v = *(const float4*)(W + (size_t)row * K_DIM + k0 + ks);
        Ws[ks + 0][h * 64 + lr] = v.x;
        Ws[ks + 1][h * 64 + lr] = v.y;
        Ws[ks + 2][h * 64 + lr] = v.z;
        Ws[ks + 3][h * 64 + lr] = v.w;
      }
    }
    __syncthreads();
#pragma unroll 8
    for (int kk = 0; kk < BK; ++kk) {
      float4 va0 = *(const float4*)&As[kk][ty * 4];
      float4 va1 = *(const float4*)&As[kk][64 + ty * 4];
      float4 vb0 = *(const float4*)&Ws[kk][tx * 4];
      float4 vb1 = *(const float4*)&Ws[kk][64 + tx * 4];
      float a0[4] = {va0.x, va0.y, va0.z, va0.w};
      float a1[4] = {va1.x, va1.y, va1.z, va1.w};
      float b0[4] = {vb0.x, vb0.y, vb0.z, vb0.w};
      float b1[4] = {vb1.x, vb1.y, vb1.z, vb1.w};
#pragma unroll
      for (int i = 0; i < 4; i++)
#pragma unroll
        for (int j = 0; j < 4; j++) {
          acc[0][0][i][j] = fmaf(a0[i], b0[j], acc[0][0][i][j]);
          acc[0][1][i][j] = fmaf(a0[i], b1[j], acc[0][1][i][j]);
          acc[1][0][i][j] = fmaf(a1[i], b0[j], acc[1][0][i][j]);
          acc[1][1][i][j] = fmaf(a1[i], b1[j], acc[1][1][i][j]);
        }
    }
    __syncthreads();
  }

#pragma unroll
  for (int mh = 0; mh < 2; ++mh)
#pragma unroll
    for (int i = 0; i < 4; i++) {
      int row = bm + mh * 64 + ty * 4 + i;
      if (row < M) {
#pragma unroll
        for (int nh = 0; nh < 2; ++nh) {
          float4 o;
          o.x = acc[mh][nh][i][0];
          o.y = acc[mh][nh][i][1];
          o.z = acc[mh][nh][i][2];
          o.w = acc[mh][nh][i][3];
          *(float4*)(H + (size_t)row * NCOLS + bn + nh * 64 + tx * 4) = o;
        }
      }
    }
}

// ---------------- column-sliced aggregation + degree-sorted order ----------------
// out[i] = dinv_i*(sum_e dinv_s*h_s) + dinv_i^2*h_i + b
// Col-group g = blockIdx.x & 7 -> XCD col-locality (R7: 124->88us).
// node = order[idx] (degree-sorted) -> uniform edge-loop trip counts per wave (R10).

template <int COLS>
__global__ __launch_bounds__(256) void aggregate_kernel(
    const float* __restrict__ H, const int* __restrict__ rowptr,
    const int* __restrict__ esrc, const float* __restrict__ ew,
    const float* __restrict__ dinv, const float* __restrict__ bias,
    const int* __restrict__ order, float* __restrict__ out, int n) {
  constexpr int CW = COLS / 8;
  constexpr int TPN = CW / 4;
  constexpr int NPB = 256 / TPN;
  const int g = blockIdx.x & 7;
  const int nb = blockIdx.x >> 3;
  const int t = threadIdx.x;
  const int ln = t / TPN;
  const int ct = t % TPN;
  const int idx = nb * NPB + ln;
  if (idx >= n) return;
  const int node = order[idx];
  const int c0 = g * CW + ct * 4;
  const float* __restrict__ Hc = H + c0;
  const float di = dinv[node];

  float4 hs = *(const float4*)(Hc + (size_t)node * COLS);
  float a0 = di * hs.x, a1 = di * hs.y, a2 = di * hs.z, a3 = di * hs.w;

  const int e1 = rowptr[node + 1];
  int e = rowptr[node];
  for (; e + 4 <= e1; e += 4) {
    int s0 = esrc[e + 0], s1 = esrc[e + 1], s2 = esrc[e + 2], s3 = esrc[e + 3];
    float w0 = ew[e + 0], w1 = ew[e + 1], w2 = ew[e + 2], w3 = ew[e + 3];
    float4 h0 = *(const float4*)(Hc + (size_t)s0 * COLS);
    float4 h1 = *(const float4*)(Hc + (size_t)s1 * COLS);
    float4 h2 = *(const float4*)(Hc + (size_t)s2 * COLS);
    float4 h3 = *(const float4*)(Hc + (size_t)s3 * COLS);
    a0 = fmaf(w3, h3.x, fmaf(w2, h2.x, fmaf(w1, h1.x, fmaf(w0, h0.x, a0))));
    a1 = fmaf(w3, h3.y, fmaf(w2, h2.y, fmaf(w1, h1.y, fmaf(w0, h0.y, a1))));
    a2 = fmaf(w3, h3.z, fmaf(w2, h2.z, fmaf(w1, h1.z, fmaf(w0, h0.z, a2))));
    a3 = fmaf(w3, h3.w, fmaf(w2, h2.w, fmaf(w1, h1.w, fmaf(w0, h0.w, a3))));
  }
  for (; e < e1; ++e) {
    int s = esrc[e];
    float w = ew[e];
    float4 h = *(const float4*)(Hc + (size_t)s * COLS);
    a0 = fmaf(w, h.x, a0);
    a1 = fmaf(w, h.y, a1);
    a2 = fmaf(w, h.z, a2);
    a3 = fmaf(w, h.w, a3);
  }

  float4 b = *(const float4*)(bias + c0);
  float4 o;
  o.x = fmaf(di, a0, b.x);
  o.y = fmaf(di, a1, b.y);
  o.z = fmaf(di, a2, b.z);
  o.w = fmaf(di, a3, b.w);
  *(float4*)(out + (size_t)node * COLS + c0) = o;
}

// ---------------- launch ----------------

extern "C" void kernel_launch(void* const* d_in, const int* in_sizes, int n_in,
                              void* d_out, int out_size, void* d_ws, size_t ws_size,
                              hipStream_t stream) {
  (void)n_in; (void)out_size; (void)ws_size;
  const float* x = (const float*)d_in[0];
  const int N = in_sizes[0] / 256;
  const int* ei = (const int*)d_in[1];
  const int E = in_sizes[1] / 2;
  const int* srcp = ei;
  const int* dstp = ei + E;
  const float* Wl[6];
  const float* Bl[6];
  for (int i = 0; i < 6; i++) {
    Wl[i] = (const float*)d_in[2 + 2 * i];
    Bl[i] = (const float*)d_in[3 + 2 * i];
  }
  float* out = (float*)d_out;

  char* p = (char*)d_ws;
  auto carve = [&](size_t bytes) {
    char* r = p;
    p += (bytes + 255) & ~(size_t)255;
    return (void*)r;
  };
  float* bufA = (float*)carve((size_t)N * 256 * 4);
  float* bufB = (float*)carve((size_t)N * 256 * 4);
  int* cnt = (int*)carve((size_t)N * 4);
  float* dinv = (float*)carve((size_t)N * 4);
  int* incl = (int*)carve((size_t)N * 4);
  int* rowptr = (int*)carve((size_t)(N + 1) * 4);
  int* esrc = (int*)carve((size_t)E * 4);
  float* ew = (float*)carve((size_t)E * 4);
  int* order = (int*)carve((size_t)N * 4);
  int* bsum = (int*)carve(1024);
  int* boff = (int*)carve(1024);
  int* bhist = (int*)carve(256);
  int* boffs = (int*)carve(256);
  int* bcur = (int*)carve(256);

  const int NB = (N + 255) / 256;

  hipMemsetAsync(cnt, 0, (size_t)N * 4, stream);
  hipMemsetAsync(bhist, 0, 256, stream);
  hipMemsetAsync(bcur, 0, 256, stream);
  hist_kernel<<<(E + 255) / 256, 256, 0, stream>>>(dstp, cnt, E);
  dinv_kernel<<<NB, 256, 0, stream>>>(cnt, dinv, N);
  scan1_kernel<<<NB, 256, 0, stream>>>(cnt, incl, bsum, N);
  scan2_kernel<<<1, 256, 0, stream>>>(bsum, boff, NB);
  scan3_kernel<<<NB, 256, 0, stream>>>(incl, boff, rowptr, N);
  bucket_hist_kernel<<<NB, 256, 0, stream>>>(cnt, bhist, N);
  bucket_scan_kernel<<<1, 64, 0, stream>>>(bhist, boffs);
  bucket_scatter_kernel<<<NB, 256, 0, stream>>>(cnt, boffs, bcur, order, N);
  hipMemsetAsync(cnt, 0, (size_t)N * 4, stream);
  scatter_kernel<<<(E + 255) / 256, 256, 0, stream>>>(srcp, dstp, rowptr, cnt, dinv,
                                                      esrc, ew, E);

  const int gm = (N + 127) / 128;
  const int gagg256 = 8 * ((N + 31) / 32);
  const int gagg128 = 8 * ((N + 63) / 64);

  // layer 1 (no lrelu on input)
  gemm_kernel<false, 256><<<dim3(gm, 2), 256, 0, stream>>>(x, Wl[0], bufB, N);
  aggregate_kernel<256><<<gagg256, 256, 0, stream>>>(bufB, rowptr, esrc, ew, dinv, Bl[0], order, bufA, N);
  // layers 2..5
  for (int l = 1; l < 5; ++l) {
    gemm_kernel<true, 256><<<dim3(gm, 2), 256, 0, stream>>>(bufA, Wl[l], bufB, N);
    aggregate_kernel<256><<<gagg256, 256, 0, stream>>>(bufB, rowptr, esrc, ew, dinv, Bl[l], order, bufA, N);
  }
  // layer 6 (out dim 128) -> d_out
  gemm_kernel<true, 128><<<dim3(gm, 1), 256, 0, stream>>>(bufA, Wl[5], bufB, N);
  aggregate_kernel<128><<<gagg128, 256, 0, stream>>>(bufB, rowptr, esrc, ew, dinv, Bl[5], order, out, N);
}

// Round 13
// 1195.862 us; speedup vs baseline: 1.3767x; 1.3767x over previous
//
#include <hip/hip_runtime.h>

#define K_DIM 256
__device__ __forceinline__ float lrelu_f(float x) { return x >= 0.f ? x : 0.2f * x; }

// ---------------- graph prep kernels ----------------

__global__ __launch_bounds__(256) void hist_kernel(const int* __restrict__ dst,
                                                   int* __restrict__ cnt, int E) {
  int e = blockIdx.x * 256 + threadIdx.x;
  if (e < E) atomicAdd(&cnt[dst[e]], 1);
}

__global__ __launch_bounds__(256) void dinv_kernel(const int* __restrict__ cnt,
                                                   float* __restrict__ dinv, int n) {
  int i = blockIdx.x * 256 + threadIdx.x;
  if (i < n) dinv[i] = rsqrtf((float)cnt[i] + 1.0f);
}

__global__ __launch_bounds__(256) void scan1_kernel(const int* __restrict__ cnt,
                                                    int* __restrict__ incl,
                                                    int* __restrict__ bsum, int n) {
  __shared__ int sm[256];
  int t = threadIdx.x;
  int i = blockIdx.x * 256 + t;
  int v = (i < n) ? cnt[i] : 0;
  sm[t] = v;
  __syncthreads();
  for (int off = 1; off < 256; off <<= 1) {
    int u = (t >= off) ? sm[t - off] : 0;
    __syncthreads();
    sm[t] += u;
    __syncthreads();
  }
  if (i < n) incl[i] = sm[t];
  if (t == 255) bsum[blockIdx.x] = sm[255];
}

__global__ __launch_bounds__(256) void scan2_kernel(const int* __restrict__ bsum,
                                                    int* __restrict__ boff, int nb) {
  __shared__ int sm[256];
  int t = threadIdx.x;
  int v = (t < nb) ? bsum[t] : 0;
  sm[t] = v;
  __syncthreads();
  for (int off = 1; off < 256; off <<= 1) {
    int u = (t >= off) ? sm[t - off] : 0;
    __syncthreads();
    sm[t] += u;
    __syncthreads();
  }
  boff[t] = sm[t] - v;  // exclusive
}

__global__ __launch_bounds__(256) void scan3_kernel(const int* __restrict__ incl,
                                                    const int* __restrict__ boff,
                                                    int* __restrict__ rowptr, int n) {
  int i = blockIdx.x * 256 + threadIdx.x;
  if (i < n) rowptr[i + 1] = incl[i] + boff[blockIdx.x];
  if (i == 0) rowptr[0] = 0;
}

__global__ __launch_bounds__(256) void scatter_kernel(const int* __restrict__ src,
                                                      const int* __restrict__ dst,
                                                      const int* __restrict__ rowptr,
                                                      int* __restrict__ cursor,
                                                      const float* __restrict__ dinv,
                                                      int* __restrict__ esrc,
                                                      float* __restrict__ ew, int E) {
  int e = blockIdx.x * 256 + threadIdx.x;
  if (e < E) {
    int d = dst[e];
    int p = rowptr[d] + atomicAdd(&cursor[d], 1);
    int s = src[e];
    esrc[p] = s;
    ew[p] = dinv[s];
  }
}

// ---------------- GEMM (R8: best known, ~100us/dispatch, 52% of fp32 peak) ----------------
// 128x128 tile, 256 threads, 8x8 microtile, BK=32, PAD=132 (2-way staging conflict).
// R9 LESSON: bigger microtile (16x8, 128thr) -> 6 waves/CU -> latency-bound, SLOWER.
// R6 LESSON: dbuf+prefetch -> VGPR 184 -> 9% occ -> 2x slower. Keep single-buffer.

template <bool LRELU, int NCOLS>
__global__ __launch_bounds__(256) void gemm_kernel(const float* __restrict__ A,
                                                   const float* __restrict__ W,
                                                   float* __restrict__ H, int M) {
  constexpr int BK = 32;
  constexpr int PAD = 132;
  __shared__ float As[BK][PAD];
  __shared__ float Ws[BK][PAD];
  const int bm = blockIdx.x * 128;
  const int bn = blockIdx.y * 128;
  const int tid = threadIdx.x;
  const int tx = tid & 15;
  const int ty = tid >> 4;
  const int lr = tid >> 2;
  const int lk = (tid & 3) << 2;

  float acc[2][2][4][4];
#pragma unroll
  for (int a = 0; a < 2; a++)
#pragma unroll
    for (int b = 0; b < 2; b++)
#pragma unroll
      for (int i = 0; i < 4; i++)
#pragma unroll
        for (int j = 0; j < 4; j++) acc[a][b][i][j] = 0.f;

  for (int k0 = 0; k0 < K_DIM; k0 += BK) {
#pragma unroll
    for (int kh = 0; kh < 2; ++kh) {
      const int ks = kh * 16 + lk;
#pragma unroll
      for (int h = 0; h < 2; ++h) {
        int row = bm + h * 64 + lr;
        int rc = row < M ? row : M - 1;
        float4 v = *(const float4*)(A + (size_t)rc * K_DIM + k0 + ks);
        if (LRELU) {
          v.x = lrelu_f(v.x); v.y = lrelu_f(v.y); v.z = lrelu_f(v.z); v.w = lrelu_f(v.w);
        }
        As[ks + 0][h * 64 + lr] = v.x;
        As[ks + 1][h * 64 + lr] = v.y;
        As[ks + 2][h * 64 + lr] = v.z;
        As[ks + 3][h * 64 + lr] = v.w;
      }
#pragma unroll
      for (int h = 0; h < 2; ++h) {
        int row = bn + h * 64 + lr;
        float4 v = *(const float4*)(W + (size_t)row * K_DIM + k0 + ks);
        Ws[ks + 0][h * 64 + lr] = v.x;
        Ws[ks + 1][h * 64 + lr] = v.y;
        Ws[ks + 2][h * 64 + lr] = v.z;
        Ws[ks + 3][h * 64 + lr] = v.w;
      }
    }
    __syncthreads();
#pragma unroll 8
    for (int kk = 0; kk < BK; ++kk) {
      float4 va0 = *(const float4*)&As[kk][ty * 4];
      float4 va1 = *(const float4*)&As[kk][64 + ty * 4];
      float4 vb0 = *(const float4*)&Ws[kk][tx * 4];
      float4 vb1 = *(const float4*)&Ws[kk][64 + tx * 4];
      float a0[4] = {va0.x, va0.y, va0.z, va0.w};
      float a1[4] = {va1.x, va1.y, va1.z, va1.w};
      float b0[4] = {vb0.x, vb0.y, vb0.z, vb0.w};
      float b1[4] = {vb1.x, vb1.y, vb1.z, vb1.w};
#pragma unroll
      for (int i = 0; i < 4; i++)
#pragma unroll
        for (int j = 0; j < 4; j++) {
          acc[0][0][i][j] = fmaf(a0[i], b0[j], acc[0][0][i][j]);
          acc[0][1][i][j] = fmaf(a0[i], b1[j], acc[0][1][i][j]);
          acc[1][0][i][j] = fmaf(a1[i], b0[j], acc[1][0][i][j]);
          acc[1][1][i][j] = fmaf(a1[i], b1[j], acc[1][1][i][j]);
        }
    }
    __syncthreads();
  }

#pragma unroll
  for (int mh = 0; mh < 2; ++mh)
#pragma unroll
    for (int i = 0; i < 4; i++) {
      int row = bm + mh * 64 + ty * 4 + i;
      if (row < M) {
#pragma unroll
        for (int nh = 0; nh < 2; ++nh) {
          float4 o;
          o.x = acc[mh][nh][i][0];
          o.y = acc[mh][nh][i][1];
          o.z = acc[mh][nh][i][2];
          o.w = acc[mh][nh][i][3];
          *(float4*)(H + (size_t)row * NCOLS + bn + nh * 64 + tx * 4) = o;
        }
      }
    }
}

// ---------------- column-sliced aggregation, 8-batch software pipeline ----------------
// out[i] = dinv_i*(sum_e dinv_s*h_s) + dinv_i^2*h_i + b
// Col-group g = blockIdx.x & 7 -> XCD col-locality (R7: 124->88us).
// LINEAR node order (R12 LESSON: degree-sorted order scattered self-reads/writes,
// 88->140us; divergence was NOT the cost).
// R13: 8-edge batches with NEXT batch's indices loaded before this batch's
// gathers are consumed -> breaks the idx-load -> gather serial chain.
// Summation order per node unchanged (ascending e) -> bit-identical.

template <int COLS>
__global__ __launch_bounds__(256) void aggregate_kernel(
    const float* __restrict__ H, const int* __restrict__ rowptr,
    const int* __restrict__ esrc, const float* __restrict__ ew,
    const float* __restrict__ dinv, const float* __restrict__ bias,
    float* __restrict__ out, int n) {
  constexpr int CW = COLS / 8;
  constexpr int TPN = CW / 4;
  constexpr int NPB = 256 / TPN;
  const int g = blockIdx.x & 7;
  const int nb = blockIdx.x >> 3;
  const int t = threadIdx.x;
  const int ln = t / TPN;
  const int ct = t % TPN;
  const int node = nb * NPB + ln;
  if (node >= n) return;
  const int c0 = g * CW + ct * 4;
  const float* __restrict__ Hc = H + c0;
  const float di = dinv[node];

  float4 hs = *(const float4*)(Hc + (size_t)node * COLS);
  float a0 = di * hs.x, a1 = di * hs.y, a2 = di * hs.z, a3 = di * hs.w;

  const int e0 = rowptr[node];
  const int e1 = rowptr[node + 1];
  int e = e0;
  const int m8 = e0 + ((e1 - e0) & ~7);

  if (e < m8) {
    int s[8];
    float w[8];
#pragma unroll
    for (int j = 0; j < 8; ++j) { s[j] = esrc[e + j]; w[j] = ew[e + j]; }
    e += 8;
    for (; e < m8; e += 8) {
      int s2[8];
      float w2[8];
#pragma unroll
      for (int j = 0; j < 8; ++j) { s2[j] = esrc[e + j]; w2[j] = ew[e + j]; }
#pragma unroll
      for (int j = 0; j < 8; ++j) {
        float4 h = *(const float4*)(Hc + (size_t)s[j] * COLS);
        a0 = fmaf(w[j], h.x, a0);
        a1 = fmaf(w[j], h.y, a1);
        a2 = fmaf(w[j], h.z, a2);
        a3 = fmaf(w[j], h.w, a3);
      }
#pragma unroll
      for (int j = 0; j < 8; ++j) { s[j] = s2[j]; w[j] = w2[j]; }
    }
#pragma unroll
    for (int j = 0; j < 8; ++j) {
      float4 h = *(const float4*)(Hc + (size_t)s[j] * COLS);
      a0 = fmaf(w[j], h.x, a0);
      a1 = fmaf(w[j], h.y, a1);
      a2 = fmaf(w[j], h.z, a2);
      a3 = fmaf(w[j], h.w, a3);
    }
  }
  for (; e < e1; ++e) {
    int s = esrc[e];
    float w = ew[e];
    float4 h = *(const float4*)(Hc + (size_t)s * COLS);
    a0 = fmaf(w, h.x, a0);
    a1 = fmaf(w, h.y, a1);
    a2 = fmaf(w, h.z, a2);
    a3 = fmaf(w, h.w, a3);
  }

  float4 b = *(const float4*)(bias + c0);
  float4 o;
  o.x = fmaf(di, a0, b.x);
  o.y = fmaf(di, a1, b.y);
  o.z = fmaf(di, a2, b.z);
  o.w = fmaf(di, a3, b.w);
  *(float4*)(out + (size_t)node * COLS + c0) = o;
}

// ---------------- launch ----------------

extern "C" void kernel_launch(void* const* d_in, const int* in_sizes, int n_in,
                              void* d_out, int out_size, void* d_ws, size_t ws_size,
                              hipStream_t stream) {
  (void)n_in; (void)out_size; (void)ws_size;
  const float* x = (const float*)d_in[0];
  const int N = in_sizes[0] / 256;
  const int* ei = (const int*)d_in[1];
  const int E = in_sizes[1] / 2;
  const int* srcp = ei;
  const int* dstp = ei + E;
  const float* Wl[6];
  const float* Bl[6];
  for (int i = 0; i < 6; i++) {
    Wl[i] = (const float*)d_in[2 + 2 * i];
    Bl[i] = (const float*)d_in[3 + 2 * i];
  }
  float* out = (float*)d_out;

  char* p = (char*)d_ws;
  auto carve = [&](size_t bytes) {
    char* r = p;
    p += (bytes + 255) & ~(size_t)255;
    return (void*)r;
  };
  float* bufA = (float*)carve((size_t)N * 256 * 4);
  float* bufB = (float*)carve((size_t)N * 256 * 4);
  int* cnt = (int*)carve((size_t)N * 4);
  float* dinv = (float*)carve((size_t)N * 4);
  int* incl = (int*)carve((size_t)N * 4);
  int* rowptr = (int*)carve((size_t)(N + 1) * 4);
  int* esrc = (int*)carve((size_t)E * 4);
  float* ew = (float*)carve((size_t)E * 4);
  int* bsum = (int*)carve(1024);
  int* boff = (int*)carve(1024);

  const int NB = (N + 255) / 256;

  hipMemsetAsync(cnt, 0, (size_t)N * 4, stream);
  hist_kernel<<<(E + 255) / 256, 256, 0, stream>>>(dstp, cnt, E);
  dinv_kernel<<<NB, 256, 0, stream>>>(cnt, dinv, N);
  scan1_kernel<<<NB, 256, 0, stream>>>(cnt, incl, bsum, N);
  scan2_kernel<<<1, 256, 0, stream>>>(bsum, boff, NB);
  scan3_kernel<<<NB, 256, 0, stream>>>(incl, boff, rowptr, N);
  hipMemsetAsync(cnt, 0, (size_t)N * 4, stream);
  scatter_kernel<<<(E + 255) / 256, 256, 0, stream>>>(srcp, dstp, rowptr, cnt, dinv,
                                                      esrc, ew, E);

  const int gm = (N + 127) / 128;
  const int gagg256 = 8 * ((N + 31) / 32);
  const int gagg128 = 8 * ((N + 63) / 64);

  // layer 1 (no lrelu on input)
  gemm_kernel<false, 256><<<dim3(gm, 2), 256, 0, stream>>>(x, Wl[0], bufB, N);
  aggregate_kernel<256><<<gagg256, 256, 0, stream>>>(bufB, rowptr, esrc, ew, dinv, Bl[0], bufA, N);
  // layers 2..5
  for (int l = 1; l < 5; ++l) {
    gemm_kernel<true, 256><<<dim3(gm, 2), 256, 0, stream>>>(bufA, Wl[l], bufB, N);
    aggregate_kernel<256><<<gagg256, 256, 0, stream>>>(bufB, rowptr, esrc, ew, dinv, Bl[l], bufA, N);
  }
  // layer 6 (out dim 128) -> d_out
  gemm_kernel<true, 128><<<dim3(gm, 1), 256, 0, stream>>>(bufA, Wl[5], bufB, N);
  aggregate_kernel<128><<<gagg128, 256, 0, stream>>>(bufB, rowptr, esrc, ew, dinv, Bl[5], out, N);
}